// Round 1
// baseline (286.464 us; speedup 1.0000x reference)
//
#include <hip/hip_runtime.h>

#define E_EDGES 32768
#define NN 8192
#define HID 128
#define KS 4

typedef _Float16 half8 __attribute__((ext_vector_type(8)));
typedef _Float16 half4 __attribute__((ext_vector_type(4)));
typedef float f32x4 __attribute__((ext_vector_type(4)));

// ---------------- CSR build (by dst), done once per call ----------------
__global__ void zero_init_k(int* __restrict__ hist, float* __restrict__ pools, int npool) {
  int t = blockIdx.x * 256 + threadIdx.x;
  if (t < NN) hist[t] = 0;
  if (t < npool) pools[t] = 0.f;
}

__global__ void hist_k(const int* __restrict__ dst, int* __restrict__ hist) {
  int e = blockIdx.x * 256 + threadIdx.x;
  if (e < E_EDGES) atomicAdd(&hist[dst[e]], 1);
}

__global__ void scan_k(const int* __restrict__ hist, int* __restrict__ roff, int* __restrict__ cursor) {
  __shared__ int ps[1024];
  int t = threadIdx.x;
  int loc[8]; int s = 0;
  int base = t * 8;
#pragma unroll
  for (int j = 0; j < 8; ++j) { loc[j] = s; s += hist[base + j]; }
  ps[t] = s;
  __syncthreads();
  for (int off = 1; off < 1024; off <<= 1) {
    int v = 0;
    if (t >= off) v = ps[t - off];
    __syncthreads();
    if (t >= off) ps[t] += v;
    __syncthreads();
  }
  int excl = (t == 0) ? 0 : ps[t - 1];
#pragma unroll
  for (int j = 0; j < 8; ++j) { int v = excl + loc[j]; roff[base + j] = v; cursor[base + j] = v; }
  if (t == 1023) roff[NN] = ps[1023];
}

__global__ void scatter_k(const int* __restrict__ dst, int* __restrict__ cursor, int* __restrict__ eidx) {
  int e = blockIdx.x * 256 + threadIdx.x;
  if (e < E_EDGES) { int p = atomicAdd(&cursor[dst[e]], 1); eidx[p] = e; }
}

// ---------------- W2 -> f16 B-matrix in MFMA-fragment-linear layout -------
// Linear padded k-space: k<128*CI theta rows (k=h*CI+i), next CI rows = b2
// (he==1 path), zero to Kpad. Layout: out[((k>>3)*CO + n)*8 + (k&7)] so a
// b-fragment (8 k x 16 n for one lane) is one contiguous 16B chunk.
template <int CI, int CO>
__device__ inline void prep_b_one(int idx, const float* __restrict__ W2,
                                  const float* __restrict__ b2, _Float16* __restrict__ out) {
  constexpr int Kmain = 128 * CI;
  int j = idx & 7;
  int n = (idx >> 3) & (CO - 1);
  int kg = idx >> (3 + (CO == 64 ? 6 : 5));
  int k = kg * 8 + j;
  float v = 0.f;
  if (k < Kmain) {
    int h = k / CI, i = k & (CI - 1);
    v = W2[(h * CI + i) * CO + n];
  } else if (k < Kmain + CI) {
    int tt = k - Kmain;
    v = b2[tt * CO + n];
  }
  out[idx] = (_Float16)v;
}

__global__ void prep_b_all_k(const float* __restrict__ W2_0, const float* __restrict__ b2_0, _Float16* __restrict__ o0,
                             const float* __restrict__ W2_1, const float* __restrict__ b2_1, _Float16* __restrict__ o1,
                             const float* __restrict__ W2_2, const float* __restrict__ b2_2, _Float16* __restrict__ o2) {
  constexpr int N0 = 2176 * 32;
  constexpr int N1 = 4224 * 64;
  constexpr int N2 = 8320 * 64;
  int idx = blockIdx.x * 256 + threadIdx.x;
  if (idx < N0) prep_b_one<16, 32>(idx, W2_0, b2_0, o0);
  else if (idx < N0 + N1) prep_b_one<32, 64>(idx - N0, W2_1, b2_1, o1);
  else if (idx < N0 + N1 + N2) prep_b_one<64, 64>(idx - N0 - N1, W2_2, b2_2, o2);
}

// ---------------- main fused kernel: edge MLP1 + Z@W2r GEMM (split-K=4) ---
// Barrier-free K-loop. A[e, h*CI+i] = he[e,h] * x[e,i] is a Khatri-Rao
// product: the x-slice per lane is K-loop-invariant (i = f(quad, c&1)), so
// x fragments are hoisted to registers ONCE, and he is read as packed
// b32/b64 per round from a transposed [e][40] LDS tile. Loop LDS traffic:
// 4 packed reads/round/wave (was 16 b128 + 16 u16) -> MFMA/B-stream-bound.
template <int CI, int CO>
__launch_bounds__(256, 2)
__global__ void msg_mfma_k(const float* __restrict__ xcur, const int* __restrict__ src,
                           const float* __restrict__ eattr, const float* __restrict__ W1,
                           const float* __restrict__ b1, const _Float16* __restrict__ Bsw,
                           float* __restrict__ msgbuf) {
  constexpr int ME = 256;                      // edges per block
  constexpr int L2CI = (CI == 64) ? 6 : ((CI == 32) ? 5 : 4);
  constexpr int XSTR = CI + 8;                 // x tile pad (preload-only now)
  constexpr int HSTR = 40;                     // he [e][40] f16: 8B-aligned rows
  constexpr int FC = CO / 16;
  constexpr int C4 = CI / 4;
  constexpr int L2C4 = L2CI - 2;
  constexpr int NMAIN = CI / 4;                // main rounds per split (all y)
  constexpr int XPN = (CI == 64) ? 2 : 1;      // x fragments per (fr): c-parity

  __shared__ _Float16 he_s[ME * HSTR];         // [e][h-local] transposed
  __shared__ _Float16 xs_s[ME * XSTR];         // [e][i]
  __shared__ float ea_s[ME * 5];
  __shared__ float W1s[5 * 32];
  __shared__ float b1s[32];
  __shared__ int src_s[ME];

  int t = threadIdx.x;
  int e0 = blockIdx.x * ME;
  int y = blockIdx.y;                          // split: h in [32y, 32y+32)
  int hbeg = y * 32;

  // phase 1: stage eattr rows, W1/b1 slice, src indices
  for (int j = t; j < ME * 5; j += 256) ea_s[j] = eattr[e0 * 5 + j];
  if (t < 5 * 32) W1s[t] = W1[(t >> 5) * HID + hbeg + (t & 31)];
  if (t < 32) b1s[t] = b1[hbeg + t];
  src_s[t] = src[e0 + t];
  __syncthreads();

  // phase 2: edge MLP1 (this split's 32 h only, transposed store) + x gather
  for (int j = t; j < 32 * ME; j += 256) {
    int hl = j >> 8, e = j & 255;
    float v = b1s[hl];
#pragma unroll
    for (int d = 0; d < 5; ++d) v += ea_s[e * 5 + d] * W1s[d * 32 + hl];
    he_s[e * HSTR + hl] = (_Float16)fmaxf(v, 0.f);
  }
  for (int j = t; j < ME * C4; j += 256) {
    int e = j >> L2C4, i4 = j & (C4 - 1);
    float4 v = ((const float4*)xcur)[src_s[e] * C4 + i4];
    half4 hq = {(_Float16)v.x, (_Float16)v.y, (_Float16)v.z, (_Float16)v.w};
    *(half4*)&xs_s[e * XSTR + i4 * 4] = hq;
  }
  __syncthreads();                             // last barrier before K-loop

  int lane = t & 63;
  int w = t >> 6;
  int quad = lane >> 4, l15 = lane & 15;
  int qsh = (quad >> 1) << 4;                  // CI==16 h-pair select shift

  int cbeg = y * CI;                           // SPLITK/32 == CI
  int cend = cbeg + CI + ((y == 3) ? 4 : 0);   // TAILK/32 == CI+4

  const half8* bsw8 = (const half8*)Bsw;
  int ib = quad * CO + l15;                    // per-lane b-frag offset

  // one-time register preload: x fragments + he row base pointers
  half8 xp[4][XPN];
  const _Float16* hbp[4];
#pragma unroll
  for (int fr = 0; fr < 4; ++fr) {
    int e = w * 64 + fr * 16 + l15;
    int i0 = (CI == 16) ? ((quad & 1) * 8) : (quad * 8);
    xp[fr][0] = *(const half8*)&xs_s[e * XSTR + i0];
    if constexpr (CI == 64) xp[fr][1] = *(const half8*)&xs_s[e * XSTR + i0 + 32];
    hbp[fr] = he_s + e * HSTR;
  }

  f32x4 acc[4][FC];
#pragma unroll
  for (int fr = 0; fr < 4; ++fr)
#pragma unroll
    for (int fc = 0; fc < FC; ++fc)
#pragma unroll
      for (int r = 0; r < 4; ++r) acc[fr][fc][r] = 0.f;

  // preload B fragments for first 4 chunks
  half8 breg[4][FC];
#pragma unroll
  for (int j = 0; j < 4; ++j)
#pragma unroll
    for (int fc = 0; fc < FC; ++fc)
      breg[j][fc] = bsw8[(cbeg + j) * 4 * CO + ib + fc * 16];

  for (int r = 0; r < NMAIN; ++r) {
    int c0 = cbeg + r * 4;
    // packed he loads for the whole round
    unsigned int hp2[4];                       // CI==64: {h0, h0+1}
    half4 hp4[4];                              // CI==32: {h0..h0+3}
    if constexpr (CI == 64) {
      int oh = (c0 >> 1) - hbeg;
#pragma unroll
      for (int fr = 0; fr < 4; ++fr) hp2[fr] = *(const unsigned int*)(hbp[fr] + oh);
    } else if constexpr (CI == 32) {
      int oh = c0 - hbeg;
#pragma unroll
      for (int fr = 0; fr < 4; ++fr) hp4[fr] = *(const half4*)(hbp[fr] + oh);
    }
#pragma unroll
    for (int j = 0; j < 4; ++j) {
      int c = c0 + j;
      half8 a[4];
#pragma unroll
      for (int fr = 0; fr < 4; ++fr) {
        if constexpr (CI == 64) {
          unsigned short hb = (unsigned short)((j >= 2) ? (hp2[fr] >> 16) : hp2[fr]);
          _Float16 hv = __builtin_bit_cast(_Float16, hb);
          a[fr] = xp[fr][j & 1] * hv;
        } else if constexpr (CI == 32) {
          a[fr] = xp[fr][0] * hp4[fr][j];
        } else {
          unsigned int hw = *(const unsigned int*)(hbp[fr] + (2 * c - hbeg));
          _Float16 hv = __builtin_bit_cast(_Float16, (unsigned short)(hw >> qsh));
          a[fr] = xp[fr][0] * hv;
        }
      }
#pragma unroll
      for (int fc = 0; fc < FC; ++fc) {
#pragma unroll
        for (int fr = 0; fr < 4; ++fr)
          acc[fr][fc] = __builtin_amdgcn_mfma_f32_16x16x32_f16(a[fr], breg[j][fc], acc[fr][fc], 0, 0, 0);
      }
      int cn = c + 4;
      if (cn >= cend) cn = cend - 1;           // clamped: branch-free prefetch
#pragma unroll
      for (int fc = 0; fc < FC; ++fc)
        breg[j][fc] = bsw8[cn * 4 * CO + ib + fc * 16];
    }
  }

  // y==3 only: single tail round (b2 rows: A = x, he == 1; zero-pad B)
  if (y == 3) {
#pragma unroll
    for (int j = 0; j < 4; ++j) {
      half8 a[4];
#pragma unroll
      for (int fr = 0; fr < 4; ++fr) a[fr] = xp[fr][(CI == 64) ? (j & 1) : 0];
#pragma unroll
      for (int fc = 0; fc < FC; ++fc) {
#pragma unroll
        for (int fr = 0; fr < 4; ++fr)
          acc[fr][fc] = __builtin_amdgcn_mfma_f32_16x16x32_f16(a[fr], breg[j][fc], acc[fr][fc], 0, 0, 0);
      }
    }
  }

  // epilogue: plain partial writes; C/D: row(e)=quad*4+r, col(o)=l15
  float* mb = msgbuf + ((size_t)y * E_EDGES + e0) * CO;
#pragma unroll
  for (int fr = 0; fr < 4; ++fr)
#pragma unroll
    for (int fc = 0; fc < FC; ++fc)
#pragma unroll
      for (int r = 0; r < 4; ++r) {
        int el = w * 64 + fr * 16 + quad * 4 + r;
        int o = fc * 16 + l15;
        mb[el * CO + o] = acc[fr][fc][r];
      }
}

// ---------------- scatter-sum via CSR gather + x@root + bias + ELU --------
// POOL=true (last layer): skip x-write, atomically accumulate subgraph pools.
template <int CI, int CO, bool POOL>
__global__ void gather_elu_k(const float* __restrict__ xcur, const float* __restrict__ root,
                             const float* __restrict__ bias, const float* __restrict__ msgbuf,
                             const int* __restrict__ roff, const int* __restrict__ eidx,
                             float* __restrict__ xnext, const int* __restrict__ n2s,
                             float* __restrict__ ssum, float* __restrict__ scnt) {
  constexpr int NB = 256 / CO;
  __shared__ float xs[NB * CI];
  int t = threadIdx.x;
  int n0 = blockIdx.x * NB;
  for (int j = t; j < NB * CI; j += 256) xs[j] = xcur[n0 * CI + j];
  __syncthreads();
  int nl = t / CO, o = t & (CO - 1);
  int n = n0 + nl;
  float a = bias[o];
#pragma unroll
  for (int i = 0; i < CI; ++i) a += xs[nl * CI + i] * root[i * CO + o];
  int j1 = roff[n + 1];
  for (int j = roff[n]; j < j1; ++j) {
    int e = eidx[j];
    float m = 0.f;
#pragma unroll
    for (int s = 0; s < KS; ++s) m += msgbuf[((size_t)s * E_EDGES + e) * CO + o];
    a += m;
  }
  float v = a > 0.f ? a : expm1f(a);
  if constexpr (POOL) {
    int s = n2s[n];
    atomicAdd(&ssum[(s << 6) + o], v);
    if (o == 0) atomicAdd(&scnt[s], 1.f);
  } else {
    xnext[n * CO + o] = v;
  }
}

// ---------------- graph pooling + MLP head (fused) ------------------------
// s2g is sorted but we just scan all 512 subgraphs from LDS (uniform branch).
__global__ void pg_head_k(const float* __restrict__ ssum, const float* __restrict__ scnt,
                          const int* __restrict__ s2g,
                          const float* __restrict__ w1, const float* __restrict__ b1,
                          const float* __restrict__ w2, const float* __restrict__ b2,
                          const float* __restrict__ w3, const float* __restrict__ b3,
                          float* __restrict__ out) {
  int g = blockIdx.x;
  int t = threadIdx.x;  // 64 threads
  __shared__ int s2s[512];
  __shared__ float hm[64], h1[32], h2[16];
  for (int i = t; i < 512; i += 64) s2s[i] = s2g[i];
  __syncthreads();
  float acc = 0.f, cnt = 0.f;
  for (int s = 0; s < 512; ++s) {
    if (s2s[s] == g) {
      acc += ssum[(s << 6) + t] / fmaxf(scnt[s], 1.f);
      cnt += 1.f;
    }
  }
  hm[t] = acc / fmaxf(cnt, 1.f);
  __syncthreads();
  if (t < 32) {
    float a = b1[t];
    for (int i = 0; i < 64; ++i) a += hm[i] * w1[i * 32 + t];
    h1[t] = a > 0.f ? a : expm1f(a);
  }
  __syncthreads();
  if (t < 16) {
    float a = b2[t];
    for (int i = 0; i < 32; ++i) a += h1[i] * w2[i * 16 + t];
    h2[t] = a > 0.f ? a : expm1f(a);
  }
  __syncthreads();
  if (t == 0) {
    float a = b3[0];
    for (int i = 0; i < 16; ++i) a += h2[i] * w3[i];
    out[g] = a;
  }
}

extern "C" void kernel_launch(void* const* d_in, const int* in_sizes, int n_in,
                              void* d_out, int out_size, void* d_ws, size_t ws_size,
                              hipStream_t stream) {
  (void)in_sizes; (void)n_in; (void)out_size; (void)ws_size;
  const float* x0 = (const float*)d_in[0];
  const int* ei = (const int*)d_in[1];
  const float* ea = (const float*)d_in[2];
  const int* n2s = (const int*)d_in[3];
  const int* s2g = (const int*)d_in[4];
  const float* W1_[3] = {(const float*)d_in[5], (const float*)d_in[11], (const float*)d_in[17]};
  const float* b1_[3] = {(const float*)d_in[6], (const float*)d_in[12], (const float*)d_in[18]};
  const float* W2_[3] = {(const float*)d_in[7], (const float*)d_in[13], (const float*)d_in[19]};
  const float* b2_[3] = {(const float*)d_in[8], (const float*)d_in[14], (const float*)d_in[20]};
  const float* rt_[3] = {(const float*)d_in[9], (const float*)d_in[15], (const float*)d_in[21]};
  const float* bs_[3] = {(const float*)d_in[10], (const float*)d_in[16], (const float*)d_in[22]};
  const float* fc1w = (const float*)d_in[23]; const float* fc1b = (const float*)d_in[24];
  const float* fc2w = (const float*)d_in[25]; const float* fc2b = (const float*)d_in[26];
  const float* fc3w = (const float*)d_in[27]; const float* fc3b = (const float*)d_in[28];
  float* out = (float*)d_out;

  const int* srcp = ei;
  const int* dstp = ei + E_EDGES;

  char* wsb = (char*)d_ws;
  size_t off = 0;
  auto alloc = [&](size_t bytes) {
    void* p = wsb + off;
    off += (bytes + 255) & ~(size_t)255;
    return p;
  };
  // Kpad: L0(CI=16): 2176, L1(CI=32): 4224, L2(CI=64): 8320
  _Float16* Bsw0 = (_Float16*)alloc((size_t)2176 * 32 * 2);
  _Float16* Bsw1 = (_Float16*)alloc((size_t)4224 * 64 * 2);
  _Float16* Bsw2 = (_Float16*)alloc((size_t)8320 * 64 * 2);
  float* msgbuf = (float*)alloc((size_t)KS * E_EDGES * 64 * 4);
  float* x1 = (float*)alloc((size_t)NN * 32 * 4);
  float* x2 = (float*)alloc((size_t)NN * 64 * 4);
  int* hist = (int*)alloc((size_t)NN * 4);
  int* roff = (int*)alloc((size_t)(NN + 1) * 4);
  int* cursor = (int*)alloc((size_t)NN * 4);
  int* eidx = (int*)alloc((size_t)E_EDGES * 4);
  const int npool = 512 * 64 + 512;
  float* pools = (float*)alloc((size_t)npool * 4);
  float* ssum = pools;
  float* scnt = pools + 512 * 64;

  zero_init_k<<<(npool + 255) / 256, 256, 0, stream>>>(hist, pools, npool);
  hist_k<<<E_EDGES / 256, 256, 0, stream>>>(dstp, hist);
  scan_k<<<1, 1024, 0, stream>>>(hist, roff, cursor);
  scatter_k<<<E_EDGES / 256, 256, 0, stream>>>(dstp, cursor, eidx);
  prep_b_all_k<<<(2176 * 32 + 4224 * 64 + 8320 * 64) / 256, 256, 0, stream>>>(
      W2_[0], b2_[0], Bsw0, W2_[1], b2_[1], Bsw1, W2_[2], b2_[2], Bsw2);

  dim3 mg(E_EDGES / 256, KS);
  msg_mfma_k<16, 32><<<mg, 256, 0, stream>>>(x0, srcp, ea, W1_[0], b1_[0], Bsw0, msgbuf);
  gather_elu_k<16, 32, false><<<NN / 8, 256, 0, stream>>>(x0, rt_[0], bs_[0], msgbuf, roff, eidx, x1, nullptr, nullptr, nullptr);
  msg_mfma_k<32, 64><<<mg, 256, 0, stream>>>(x1, srcp, ea, W1_[1], b1_[1], Bsw1, msgbuf);
  gather_elu_k<32, 64, false><<<NN / 4, 256, 0, stream>>>(x1, rt_[1], bs_[1], msgbuf, roff, eidx, x2, nullptr, nullptr, nullptr);
  msg_mfma_k<64, 64><<<mg, 256, 0, stream>>>(x2, srcp, ea, W1_[2], b1_[2], Bsw2, msgbuf);
  gather_elu_k<64, 64, true><<<NN / 4, 256, 0, stream>>>(x2, rt_[2], bs_[2], msgbuf, roff, eidx, nullptr, n2s, ssum, scnt);

  pg_head_k<<<32, 64, 0, stream>>>(ssum, scnt, s2g, fc1w, fc1b, fc2w, fc2b, fc3w, fc3b, out);
}